// Round 3
// baseline (357.619 us; speedup 1.0000x reference)
//
#include <hip/hip_runtime.h>
#include <math.h>

#define N_TOK   16384
#define K_TOT   (8 * N_TOK)      // 131072 reduction rows per batch
#define N_BATCH 4
#define BPB     128              // K1 blocks per batch
#define RPB     (K_TOT / BPB)    // 1024 contiguous rows per block
#define CHUNK   64               // rows per LDS chunk
#define NCH     (RPB / CHUNK)    // 16 chunks per block

// ---------------------------------------------------------------------------
// K1 (rewritten): fp32 outer-product stream, NO MFMA / NO bf16 split.
//   C[c][d] += sum_tok K[tok][c] * V[tok][d]
// Rationale (round-2 counters): warm-L3 replay ran at the SAME 100us as cold
// -> old k1 was internally stalled (phase-convoyed LDS/VALU storms around the
// per-chunk barrier), not memory-bound. fp32 FMA work is 27us at vector rate,
// under the 43us HBM floor, so a simple outer-product stream is HBM-bound.
//   - staging: global_load_lds dwordx4, linear [row][ch] layout (no transpose,
//     no conversion, no register round-trip): 4 instrs per wave per chunk.
//   - compute: thread (c4,d4) owns a 4x4 tile; per token: 1 broadcast
//     ds_read_b128 of K[4], 1 of V[4], 16 v_fmac_f32. Token-row offsets are
//     compile-time immediates (fully unrolled 32-token loop).
//   - halves: threads 0-255 process tokens 0-31 of each chunk, 256-511 tokens
//     32-63; partials combined through LDS at the end.
//   - pipeline: stage(ch+1) issued before compute(ch); vmcnt(0)+barrier per
//     chunk. Loads fly under the ~4K-cycle FMA phase.
// ---------------------------------------------------------------------------

typedef float f32x4 __attribute__((ext_vector_type(4)));

__device__ __forceinline__ void gload16(const float* g, float* l) {
  __builtin_amdgcn_global_load_lds(
      (const __attribute__((address_space(1))) void*)g,
      (__attribute__((address_space(3))) void*)l, 16, 0, 0);
}

// s_waitcnt masks (gfx9 encoding): vmcnt[3:0]=b3:0, exp=b6:4, lgkm=b11:8,
// vmcnt[5:4]=b15:14.  no-wait: vmcnt=63, exp=7, lgkm=15.
#define WAIT_VM0   0x0F70u   // vmcnt(0), exp/lgkm no-wait
#define WAIT_LGKM0 0xC07Fu   // lgkmcnt(0), vm/exp no-wait

__global__ __launch_bounds__(512, 2) void k1_outer(
    const float* __restrict__ key, const float* __restrict__ val,
    float* __restrict__ part) {
  __shared__ float lds[2][8192];   // 64 KiB: [par][ K 64x64 | V 64x64 ]

  int blk  = blockIdx.x;
  int b    = blk / BPB;
  int p    = blk % BPB;
  int t    = threadIdx.x;
  int wave = t >> 6;
  int lane = t & 63;

  size_t base = ((size_t)b * K_TOT + (size_t)p * RPB) * 64;  // float offset

  // staging role: waves 0-3 stage K, waves 4-7 stage V; 4 KiB-units per wave
  const float* sarr = (wave < 4) ? (key + base) : (val + base);
  uint ldsarr = (wave < 4) ? 0u : 4096u;
  uint uoff   = (uint)((wave & 3) * 1024);     // float offset of this wave's 4KB

  // compute role: half 0 -> tokens 0..31, half 1 -> tokens 32..63 of chunk
  int half = t >> 8;
  int tid  = t & 255;
  int c4   = tid >> 4;     // 0..15
  int d4   = tid & 15;     // 0..15
  int r0   = half * 32;

  float acc[4][4];
#pragma unroll
  for (int i = 0; i < 4; i++)
#pragma unroll
    for (int j = 0; j < 4; j++) acc[i][j] = 0.f;

  auto stage = [&](int ch, int par) {
    const float* g = sarr + (size_t)ch * (CHUNK * 64) + uoff + lane * 4;
    float* l = &lds[par][ldsarr + uoff];
#pragma unroll
    for (int q = 0; q < 4; q++)
      gload16(g + q * 256, l + q * 256);   // lds dest wave-uniform; HW adds lane*16
  };

  auto compute = [&](int par) {
    const float* Kb = &lds[par][(r0 << 6) + c4 * 4];
    const float* Vb = &lds[par][4096 + (r0 << 6) + d4 * 4];
#pragma unroll
    for (int r = 0; r < 32; r++) {
      float4 kk = *(const float4*)&Kb[r * 64];
      float4 vv = *(const float4*)&Vb[r * 64];
#pragma unroll
      for (int i = 0; i < 4; i++)
#pragma unroll
        for (int j = 0; j < 4; j++)
          acc[i][j] = fmaf((&kk.x)[i], (&vv.x)[j], acc[i][j]);
    }
  };

  // prologue: chunk 0 into buf 0
  stage(0, 0);
  asm volatile("" ::: "memory");
  __builtin_amdgcn_s_waitcnt(WAIT_VM0);
  __builtin_amdgcn_s_barrier();
  asm volatile("" ::: "memory");

#pragma unroll 2
  for (int ch = 0; ch < NCH; ch++) {
    if (ch + 1 < NCH) stage(ch + 1, (ch + 1) & 1);  // writes OTHER buffer
    compute(ch & 1);                                // own reads done by use
    asm volatile("" ::: "memory");
    __builtin_amdgcn_s_waitcnt(WAIT_VM0);           // stage(ch+1) landed
    __builtin_amdgcn_s_barrier();                   // everyone done with buf[ch&1]
    asm volatile("" ::: "memory");
  }

  // combine halves via LDS (buf 0 is idle: last compute read buf 1)
  float* scratch = &lds[0][0];
  if (half) {
#pragma unroll
    for (int i = 0; i < 4; i++)
      *(float4*)&scratch[tid * 20 + i * 4] =
          make_float4(acc[i][0], acc[i][1], acc[i][2], acc[i][3]);
  }
  asm volatile("" ::: "memory");
  __builtin_amdgcn_s_waitcnt(WAIT_LGKM0);
  __builtin_amdgcn_s_barrier();
  asm volatile("" ::: "memory");
  if (!half) {
    float* dst = part + (size_t)blk * 4096;
#pragma unroll
    for (int i = 0; i < 4; i++) {
      float4 s = *(const float4*)&scratch[tid * 20 + i * 4];
      float4 o = make_float4(acc[i][0] + s.x, acc[i][1] + s.y,
                             acc[i][2] + s.z, acc[i][3] + s.w);
      *(float4*)&dst[(c4 * 4 + i) * 64 + d4 * 4] = o;
    }
  }
}

// ---------------------------------------------------------------------------
// K2: reduce 128 partial tiles per batch -> kv[b][c][d].
// ---------------------------------------------------------------------------
__global__ __launch_bounds__(256, 4) void k2_reduce(
    const float* __restrict__ part, float* __restrict__ kv, int bpb) {
  int b  = blockIdx.x >> 6;
  int c  = blockIdx.x & 63;
  int p4 = threadIdx.x >> 6;
  int d  = threadIdx.x & 63;

  float s = 0.f;
  int iters = bpb >> 2;
  const float* src = part + (size_t)(b * bpb) * 4096 + c * 64 + d;
#pragma unroll 4
  for (int x = 0; x < iters; x++) s += src[(size_t)(p4 + 4 * x) * 4096];

  __shared__ float l[256];
  l[threadIdx.x] = s;
  __syncthreads();
  if (p4 == 0)
    kv[((size_t)b * 64 + c) * 64 + d] = l[d] + l[64 + d] + l[128 + d] + l[192 + d];
}

// ---------------------------------------------------------------------------
// K3: fused softmax + out (unchanged from round 2, verified).
//   e[c][d]   = exp(kv[b][c][d] - max_c kv[b][:,d])   (unnormalized)
//   out[b,m,d]= (alpha/den[d]) * sum_c key_cur[b,m,c]*e[c][d] + val_cur[b,m,d]
// ---------------------------------------------------------------------------
__global__ __launch_bounds__(256, 4) void k3_out(
    const float* __restrict__ kv, const float* __restrict__ keyc,
    const float* __restrict__ valc, const float* __restrict__ alphap,
    float* __restrict__ out) {
  __shared__ float Ps[4096];       // e = exp(kv - mx[d])
  __shared__ float kT[64 * 68];
  __shared__ float redm[4][64];    // per-group partial max over c
  __shared__ float reds[4][64];    // per-group partial sum of e over c

  int bb = blockIdx.x >> 8;
  int mb = blockIdx.x & 255;
  int m0 = mb * 64;
  int t = threadIdx.x;

  // softmax role: thread (cg, d) reduces c = cg*16 .. cg*16+15 of column d
  int d  = t & 63;
  int cg = t >> 6;
  const float* kvb = kv + (size_t)bb * 4096;
  float v[16];
  float mx = -3.0e38f;
#pragma unroll
  for (int i = 0; i < 16; i++) {
    v[i] = kvb[(cg * 16 + i) * 64 + d];
    mx = fmaxf(mx, v[i]);
  }
  redm[cg][d] = mx;

  // kT staging (independent of softmax; same barrier covers both)
  int r  = t >> 2;
  int cb = (t & 3) * 16;
  const float* krow = keyc + ((size_t)bb * N_TOK + m0 + r) * 64;
#pragma unroll
  for (int u = 0; u < 4; u++) {
    float4 kk = *(const float4*)&krow[cb + 4 * u];
    int c = cb + 4 * u;
    kT[(c + 0) * 68 + r] = kk.x;
    kT[(c + 1) * 68 + r] = kk.y;
    kT[(c + 2) * 68 + r] = kk.z;
    kT[(c + 3) * 68 + r] = kk.w;
  }
  __syncthreads();

  mx = fmaxf(fmaxf(redm[0][d], redm[1][d]), fmaxf(redm[2][d], redm[3][d]));
  float s = 0.f;
#pragma unroll
  for (int i = 0; i < 16; i++) {
    float e = __expf(v[i] - mx);
    Ps[(cg * 16 + i) * 64 + d] = e;
    s += e;
  }
  reds[cg][d] = s;
  __syncthreads();

  int wave = t >> 6, lane = t & 63;
  int mi = lane >> 3, j = lane & 7;
  int m = wave * 16 + mi * 2;

  float acc[2][8];
#pragma unroll
  for (int a = 0; a < 2; a++)
#pragma unroll
    for (int dd = 0; dd < 8; dd++) acc[a][dd] = 0.f;

#pragma unroll 4
  for (int c = 0; c < 64; c++) {
    float2 kk = *(const float2*)&kT[c * 68 + m];
    float4 p0 = *(const float4*)&Ps[c * 64 + 8 * j];
    float4 p1 = *(const float4*)&Ps[c * 64 + 8 * j + 4];
    float pr[8] = {p0.x, p0.y, p0.z, p0.w, p1.x, p1.y, p1.z, p1.w};
#pragma unroll
    for (int dd = 0; dd < 8; dd++) {
      acc[0][dd] = fmaf(kk.x, pr[dd], acc[0][dd]);
      acc[1][dd] = fmaf(kk.y, pr[dd], acc[1][dd]);
    }
  }

  float alpha = alphap[0];
  float sc[8];
#pragma unroll
  for (int dd = 0; dd < 8; dd++) {
    int dq = 8 * j + dd;
    float den = reds[0][dq] + reds[1][dq] + reds[2][dq] + reds[3][dq];
    sc[dd] = alpha / den;
  }

#pragma unroll
  for (int a = 0; a < 2; a++) {
    size_t off = ((size_t)bb * N_TOK + m0 + m + a) * 64 + 8 * j;
    float4 v0 = *(const float4*)&valc[off];
    float4 v1 = *(const float4*)&valc[off + 4];
    float4 o0 = make_float4(fmaf(sc[0], acc[a][0], v0.x),
                            fmaf(sc[1], acc[a][1], v0.y),
                            fmaf(sc[2], acc[a][2], v0.z),
                            fmaf(sc[3], acc[a][3], v0.w));
    float4 o1 = make_float4(fmaf(sc[4], acc[a][4], v1.x),
                            fmaf(sc[5], acc[a][5], v1.y),
                            fmaf(sc[6], acc[a][6], v1.z),
                            fmaf(sc[7], acc[a][7], v1.w));
    *(float4*)&out[off] = o0;
    *(float4*)&out[off + 4] = o1;
  }
}

// ---------------------------------------------------------------------------
extern "C" void kernel_launch(void* const* d_in, const int* in_sizes, int n_in,
                              void* d_out, int out_size, void* d_ws,
                              size_t ws_size, hipStream_t stream) {
  const float* key_mem = (const float*)d_in[0];
  const float* val_mem = (const float*)d_in[1];
  const float* key_cur = (const float*)d_in[2];
  const float* val_cur = (const float*)d_in[3];
  const float* alpha   = (const float*)d_in[4];
  float* out = (float*)d_out;
  float* ws  = (float*)d_ws;

  float* part = ws;                                    // 512 tiles (8.4 MB)
  float* kv   = ws + (size_t)(N_BATCH * BPB) * 4096;   // 4 tiles

  k1_outer<<<N_BATCH * BPB, 512, 0, stream>>>(key_mem, val_mem, part);
  k2_reduce<<<256, 256, 0, stream>>>(part, kv, BPB);
  k3_out<<<N_BATCH * (N_TOK / 64), 256, 0, stream>>>(kv, key_cur, val_cur,
                                                     alpha, out);
}